// Round 18
// baseline (405.388 us; speedup 1.0000x reference)
//
#include <hip/hip_runtime.h>
#include <hip/hip_bf16.h>

// out[B,S,O] = A[B,S,I] @ W[O,I]^T * scales[O] + bias[O]
// M = 16384, N = 4096, K = 4096. Output fp32.
// i8 path: A per-row quant (amax/127), W exact i8; mfma_i32_16x16x64_i8;
// dequant epilogue acc * (ascale[m]*scales[n]) + bias[n].
// R18 vs R17: 4-wave blocks (256 thr), tile 256x128, per-wave 128x64 output
// (identical acc/QUAD/fragment structure). At 256 regs/wave (128 VGPR +
// 128 acc) the file allows 2 waves/SIMD; with 4-wave blocks that is TWO
// independent blocks/CU -> their barrier phases drift and one block's MFMA
// fills the other's read/barrier stall (m114). R16/R17 were pinned to ONE
// 8-wave block by the register file, not LDS.
#define M_TOTAL 16384
#define N_TOTAL 4096
#define K_TOTAL 4096
#define NT (K_TOTAL / 64)  // 64 K-tiles of BK=64 (i8)
#define W_BLOCKS 2048

typedef __attribute__((ext_vector_type(4))) int i32x4;

__device__ __forceinline__ unsigned pack4(int a, int b, int c, int d) {
  return (a & 0xFF) | ((b & 0xFF) << 8) | ((c & 0xFF) << 16) | ((d & 0xFF) << 24);
}

// ---- fused conversions: blocks [0,W_BLOCKS) pack W, rest quantize A rows ----
__global__ __launch_bounds__(256) void cvt_fused(
    const float* __restrict__ A, unsigned* __restrict__ Aq,
    float* __restrict__ ascale, const int* __restrict__ W,
    unsigned* __restrict__ Wq) {
  const int tid = threadIdx.x;
  if (blockIdx.x < W_BLOCKS) {
    const int n4 = (N_TOTAL * K_TOTAL) / 4;
    const int stride = W_BLOCKS * 256;
    for (int i = blockIdx.x * 256 + tid; i < n4; i += stride) {
      int4 v = reinterpret_cast<const int4*>(W)[i];
      Wq[i] = pack4(v.x, v.y, v.z, v.w);
    }
    return;
  }
  const int row = blockIdx.x - W_BLOCKS;
  const float4* src = reinterpret_cast<const float4*>(A + (size_t)row * K_TOTAL);
  float4 v[4];
#pragma unroll
  for (int c = 0; c < 4; ++c) v[c] = src[tid + 256 * c];
  float amax = 0.0f;
#pragma unroll
  for (int c = 0; c < 4; ++c)
    amax = fmaxf(amax, fmaxf(fmaxf(fabsf(v[c].x), fabsf(v[c].y)),
                             fmaxf(fabsf(v[c].z), fabsf(v[c].w))));
#pragma unroll
  for (int off = 32; off > 0; off >>= 1) amax = fmaxf(amax, __shfl_xor(amax, off, 64));
  __shared__ float wmax[4];
  if ((tid & 63) == 0) wmax[tid >> 6] = amax;
  __syncthreads();
  amax = fmaxf(fmaxf(wmax[0], wmax[1]), fmaxf(wmax[2], wmax[3]));
  amax = fmaxf(amax, 1e-20f);
  const float rs = 127.0f / amax;
  if (tid == 0) ascale[row] = amax * (1.0f / 127.0f);

  unsigned* dst = Aq + (size_t)row * (K_TOTAL / 4);
#pragma unroll
  for (int c = 0; c < 4; ++c) {
    int q[4];
    float f[4] = {v[c].x, v[c].y, v[c].z, v[c].w};
#pragma unroll
    for (int i = 0; i < 4; ++i) {
      int t = (int)rintf(f[i] * rs);
      q[i] = t < -127 ? -127 : (t > 127 ? 127 : t);
    }
    dst[tid + 256 * c] = pack4(q[0], q[1], q[2], q[3]);
  }
}

// ======== 256x128 i8 GEMM — R7/R17 skeleton, 4-wave blocks (R18) ========
#define GLOAD_LDS16(gp, lp)                                                \
  __builtin_amdgcn_global_load_lds(                                        \
      (const __attribute__((address_space(1))) void*)(gp),                 \
      (__attribute__((address_space(3))) void*)(lp), 16, 0, 0)

#define BAR() asm volatile("s_barrier" ::: "memory")
#define VM(n) asm volatile("s_waitcnt vmcnt(" #n ")" ::: "memory")

// LDS map (49152 B): buf b at b*24576: A_h0 [0,8K) A_h1 [8K,16K)
// B_h0 [16K,20K) B_h1 [20K,24K). Rows are 64 B (BK=64 i8).
// Swizzle (R17-proven): 16B block c of row r stored at c ^ ((r>>1)&3);
// fragment reads are 2-way bank aliased = free (m136). gload_lds writes
// linearly; GLOBAL source col-block inverse-swizzled: (l&3)^((l>>3)&3)
// (rows per instr = w*16+(l>>2); (row>>1)&3 == (l>>3)&3 since w*8 % 4 == 0).
// Stages (R7 slots; A-half = 2 instrs, B-half = 1): P1: Ah1(t+1)->nxt;
// P2: Bh0(t+2)->cur; P3: Bh1(t+2)->cur; P4: Ah0(t+2)->cur.
// Ledger: invariant at P1 head: [Bh0(t+1) 1, Bh1(t+1) 1, Ah0(t+1) 2] = 4,
// tile t landed. P1+2=6, P2+1=7, P3+1=8, P4+2=10 -> VM(4)@P4-end drains the
// 6 oldest = tile t+1 exactly. Prologue: 10 loads -> VM(4) drains tile0.
// Fences precede barriers; reads sit in their consuming phase (race-free,
// inherited from the twice-proven R7 structure; swizzle proven in R17).

__global__ __launch_bounds__(256, 2) void w8a16_gemm_i8(
    const signed char* __restrict__ A,   // [M][K] i8
    const signed char* __restrict__ Bt,  // [N][K] i8
    const float* __restrict__ ascale,    // [M]
    const float* __restrict__ scales, const float* __restrict__ bias,
    float* __restrict__ C) {
  __shared__ alignas(16) unsigned char lds[49152];

  const int tid = threadIdx.x;
  const int w = tid >> 6, l = tid & 63;
  const int wr = w >> 1, wc = w & 1;  // 2x2 wave grid; per-wave 128x64 output
  const int bn = blockIdx.x, bm = blockIdx.y;

  // staging address (pre-inverse-swizzled source)
  const int rowq = tid >> 2;                           // w*16 + (l>>2), 0..63
  const int colb = (((l & 3) ^ ((l >> 3) & 3)) << 4);  // col byte block
  const signed char* pA = A + (size_t)(bm * 256 + rowq) * K_TOTAL + colb;
  const signed char* pB = Bt + (size_t)(bn * 128 + rowq) * K_TOTAL + colb;
  unsigned char* const ldsp = lds;
  const int woff = w << 10;

#define SDA(b_, h_) (ldsp + (b_) * 24576 + (h_) * 8192 + woff)
#define SDB(b_, h_) (ldsp + (b_) * 24576 + 16384 + (h_) * 4096 + woff)
#define STAGE_A(b_, h_, t_)                                                    \
  do {                                                                         \
    GLOAD_LDS16(pA + (size_t)((h_) * 128) * K_TOTAL + (t_) * 64, SDA(b_, h_)); \
    GLOAD_LDS16(pA + (size_t)((h_) * 128 + 64) * K_TOTAL + (t_) * 64,          \
                SDA(b_, h_) + 4096);                                           \
  } while (0)
#define STAGE_B(b_, h_, t_)                                                    \
  GLOAD_LDS16(pB + (size_t)((h_) * 64) * K_TOTAL + (t_) * 64, SDB(b_, h_))

  // fragment read: row (l&15) in frag, k-block (l>>4), swizzle (l>>1)&3
  const int arow = ((l & 15) << 6) + ((((l >> 4) ^ (l >> 1)) & 3) << 4);

  i32x4 af[4];   // current m-half: 4 m-frags (full K=64 slice each)
  i32x4 bfr[4];  // whole-tile B: 4 n-frags
  i32x4 acc[8][4] = {{}};

#define RD_A(mh_)                                                             \
  do {                                                                        \
    const unsigned char* Ab_ = ldsp + bsel * 24576 + wr * 8192;               \
    _Pragma("unroll") for (int fm = 0; fm < 4; ++fm)                          \
        af[fm] = *(const i32x4*)(Ab_ + ((mh_) * 4 + fm) * 1024 + arow);       \
  } while (0)
#define RD_B(nh_)                                                             \
  do {                                                                        \
    const unsigned char* Bb_ = ldsp + bsel * 24576 + 16384 + wc * 4096;       \
    _Pragma("unroll") for (int fn = 0; fn < 2; ++fn)                          \
        bfr[(nh_) * 2 + fn] =                                                 \
            *(const i32x4*)(Bb_ + ((nh_) * 2 + fn) * 1024 + arow);            \
  } while (0)
#define QUAD(mh_, nh_)                                                        \
  do {                                                                        \
    __builtin_amdgcn_s_setprio(1);                                            \
    _Pragma("unroll") for (int m = 0; m < 4; ++m)                             \
        _Pragma("unroll") for (int n = 0; n < 2; ++n)                         \
            acc[(mh_) * 4 + m][(nh_) * 2 + n] =                               \
                __builtin_amdgcn_mfma_i32_16x16x64_i8(                        \
                    af[m], bfr[(nh_) * 2 + n],                                \
                    acc[(mh_) * 4 + m][(nh_) * 2 + n], 0, 0, 0);              \
    __builtin_amdgcn_s_setprio(0);                                            \
  } while (0)

  // --- prologue: tile0 (6) + B(1)h0,h1 (2) + A(1)h0 (2) = 10; VM(4) ---
  STAGE_A(0, 0, 0); STAGE_A(0, 1, 0);
  STAGE_B(0, 0, 0); STAGE_B(0, 1, 0);
  STAGE_B(1, 0, 1); STAGE_B(1, 1, 1);
  STAGE_A(1, 0, 1);
  VM(4);
  BAR();

  // --- main loop (R7 structure): 4 phases/tile, reads in consuming phase ---
  for (int t = 0; t < NT; ++t) {
    const int bsel = t & 1;
    // P1
    RD_A(0); RD_B(0);
    if (t + 1 < NT) STAGE_A(bsel ^ 1, 1, t + 1);
    BAR();
    QUAD(0, 0);
    BAR();
    // P2
    RD_B(1);
    if (t + 2 < NT) STAGE_B(bsel, 0, t + 2);
    BAR();
    QUAD(0, 1);
    BAR();
    // P3
    RD_A(1);
    if (t + 2 < NT) STAGE_B(bsel, 1, t + 2);
    BAR();
    QUAD(1, 1);
    BAR();
    // P4 (B-frags reused from registers)
    if (t + 2 < NT) STAGE_A(bsel, 0, t + 2);
    BAR();
    QUAD(1, 0);
    if (t < NT - 2) { VM(4); } else { VM(0); }
    BAR();
  }

  // --- epilogue: C/D col=lane&15, row=(lane>>4)*4+reg (dtype-independent);
  //     dequant acc * (ascale[row]*scales[col]) + bias ---
  const int row0 = bm * 256 + wr * 128 + ((l >> 4) << 2);
  const int col0 = bn * 128 + wc * 64 + (l & 15);
#pragma unroll
  for (int fn = 0; fn < 4; ++fn) {
    const int col = col0 + fn * 16;
    const float sc = scales[col];
    const float bi = bias[col];
#pragma unroll
    for (int fm = 0; fm < 8; ++fm) {
      const int r = row0 + fm * 16;
      float* cp = C + (size_t)r * N_TOTAL + col;
#pragma unroll
      for (int j = 0; j < 4; ++j)
        cp[(size_t)j * N_TOTAL] = fmaf((float)acc[fm][fn][j], ascale[r + j] * sc, bi);
    }
  }
}

// ---- guarded fallback (only if d_ws too small) ----
__global__ void naive_gemm(const float* __restrict__ A, const int* __restrict__ W,
                           const float* __restrict__ scales, const float* __restrict__ bias,
                           float* __restrict__ C) {
  size_t idx = (size_t)blockIdx.x * blockDim.x + threadIdx.x;
  if (idx >= (size_t)M_TOTAL * N_TOTAL) return;
  const int n = (int)(idx % N_TOTAL);
  const size_t m = idx / N_TOTAL;
  const float* a = A + m * (size_t)K_TOTAL;
  const int* w = W + (size_t)n * K_TOTAL;
  float s = 0.f;
  for (int k = 0; k < K_TOTAL; ++k) s = fmaf(a[k], (float)w[k], s);
  C[idx] = fmaf(s, scales[n], bias[n]);
}

extern "C" void kernel_launch(void* const* d_in, const int* in_sizes, int n_in,
                              void* d_out, int out_size, void* d_ws, size_t ws_size,
                              hipStream_t stream) {
  const float* A = (const float*)d_in[0];
  const int* W = (const int*)d_in[1];
  const float* scales = (const float*)d_in[2];
  const float* bias = (const float*)d_in[3];
  float* out = (float*)d_out;

  const size_t a_elems = (size_t)M_TOTAL * K_TOTAL;
  const size_t w_elems = (size_t)N_TOTAL * K_TOTAL;
  const size_t need = a_elems + w_elems + (size_t)M_TOTAL * sizeof(float);

  if (ws_size >= need) {
    signed char* A_q = (signed char*)d_ws;
    signed char* W_q = A_q + a_elems;
    float* a_s = (float*)(W_q + w_elems);
    cvt_fused<<<W_BLOCKS + M_TOTAL, 256, 0, stream>>>(A, (unsigned*)A_q, a_s, W,
                                                      (unsigned*)W_q);
    dim3 grid(N_TOTAL / 128, M_TOTAL / 256);  // (32, 64) = 2048 blocks
    w8a16_gemm_i8<<<grid, 256, 0, stream>>>(A_q, W_q, a_s, scales, bias, out);
  } else {
    size_t total = (size_t)M_TOTAL * N_TOTAL;
    naive_gemm<<<(unsigned)((total + 255) / 256), 256, 0, stream>>>(A, W, scales, bias, out);
  }
}

// Round 19
// 363.407 us; speedup vs baseline: 1.1155x; 1.1155x over previous
//
#include <hip/hip_runtime.h>
#include <hip/hip_bf16.h>

// out[B,S,O] = A[B,S,I] @ W[O,I]^T * scales[O] + bias[O]
// M = 16384, N = 4096, K = 4096. Output fp32.
// i8 path: A per-row quant (amax/127), W exact i8; mfma_i32_16x16x64_i8;
// dequant epilogue acc * (ascale[m]*scales[n]) + bias[n].
// R19 = R16 (best verified: GEMM 289us, total 374.9us) minus s_setprio.
// m190 evidence: setprio is NEGATIVE on barrier-lockstep GEMM (T5 needs
// phase-role-split waves; this structure is deliberately lockstep).
// Structural note: per-tile cost is additive (LDS 2304 + MFMA 2722 + ~400
// cyc, measured 5437); LDS reads are geometry-minimal; cross-block overlap
// is bounded by the shared per-CU LDS pipe (R18); intra-block pipelining
// exceeded the register budget or raced in 10/10 attempts (R4-R15, R18).
#define M_TOTAL 16384
#define N_TOTAL 4096
#define K_TOTAL 4096
#define NT (K_TOTAL / 128)  // 32 K-tiles of BK=128 (i8)
#define W_BLOCKS 2048

typedef __attribute__((ext_vector_type(4))) int i32x4;

__device__ __forceinline__ unsigned pack4(int a, int b, int c, int d) {
  return (a & 0xFF) | ((b & 0xFF) << 8) | ((c & 0xFF) << 16) | ((d & 0xFF) << 24);
}

// ---- fused conversions: blocks [0,W_BLOCKS) pack W, rest quantize A rows ----
__global__ __launch_bounds__(256) void cvt_fused(
    const float* __restrict__ A, unsigned* __restrict__ Aq,
    float* __restrict__ ascale, const int* __restrict__ W,
    unsigned* __restrict__ Wq) {
  const int tid = threadIdx.x;
  if (blockIdx.x < W_BLOCKS) {
    const int n4 = (N_TOTAL * K_TOTAL) / 4;
    const int stride = W_BLOCKS * 256;
    for (int i = blockIdx.x * 256 + tid; i < n4; i += stride) {
      int4 v = reinterpret_cast<const int4*>(W)[i];
      Wq[i] = pack4(v.x, v.y, v.z, v.w);
    }
    return;
  }
  const int row = blockIdx.x - W_BLOCKS;
  const float4* src = reinterpret_cast<const float4*>(A + (size_t)row * K_TOTAL);
  float4 v[4];
#pragma unroll
  for (int c = 0; c < 4; ++c) v[c] = src[tid + 256 * c];
  float amax = 0.0f;
#pragma unroll
  for (int c = 0; c < 4; ++c)
    amax = fmaxf(amax, fmaxf(fmaxf(fabsf(v[c].x), fabsf(v[c].y)),
                             fmaxf(fabsf(v[c].z), fabsf(v[c].w))));
#pragma unroll
  for (int off = 32; off > 0; off >>= 1) amax = fmaxf(amax, __shfl_xor(amax, off, 64));
  __shared__ float wmax[4];
  if ((tid & 63) == 0) wmax[tid >> 6] = amax;
  __syncthreads();
  amax = fmaxf(fmaxf(wmax[0], wmax[1]), fmaxf(wmax[2], wmax[3]));
  amax = fmaxf(amax, 1e-20f);
  const float rs = 127.0f / amax;
  if (tid == 0) ascale[row] = amax * (1.0f / 127.0f);

  unsigned* dst = Aq + (size_t)row * (K_TOTAL / 4);
#pragma unroll
  for (int c = 0; c < 4; ++c) {
    int q[4];
    float f[4] = {v[c].x, v[c].y, v[c].z, v[c].w};
#pragma unroll
    for (int i = 0; i < 4; ++i) {
      int t = (int)rintf(f[i] * rs);
      q[i] = t < -127 ? -127 : (t > 127 ? 127 : t);
    }
    dst[tid + 256 * c] = pack4(q[0], q[1], q[2], q[3]);
  }
}

// ======== 256x256 i8 GEMM — R7/R16 skeleton, no setprio (R19) ========
#define GLOAD_LDS16(gp, lp)                                                \
  __builtin_amdgcn_global_load_lds(                                        \
      (const __attribute__((address_space(1))) void*)(gp),                 \
      (__attribute__((address_space(3))) void*)(lp), 16, 0, 0)

#define BAR() asm volatile("s_barrier" ::: "memory")
#define VM(n) asm volatile("s_waitcnt vmcnt(" #n ")" ::: "memory")

// LDS map (131072 B): buf b at b*65536: A_h0 [0,16K) A_h1 [16K,32K)
// B_h0 [32K,48K) B_h1 [48K,64K). Half-tile = 128 rows x 128 i8, stride 128 B.
// Swizzle: (r,c) at byte r*128 + (c ^ ((r&7)<<4)) (involution, 16B blocks).
// gload_lds writes linearly; GLOBAL source pre-inverse-swizzled (rule #21).
// Ledger at P1 head: outstanding {Bh0(t+1),Bh1(t+1),Ah0(t+1)}=6, tile t
// landed. VM(6)@P4-end completes tile t+1 (incl. Ah1(t+1) staged at P1).
// Fences precede barriers; reads sit in their consuming phase (race-free).

__global__ __launch_bounds__(512, 2) void w8a16_gemm_i8(
    const signed char* __restrict__ A,   // [M][K] i8
    const signed char* __restrict__ Bt,  // [N][K] i8
    const float* __restrict__ ascale,    // [M]
    const float* __restrict__ scales, const float* __restrict__ bias,
    float* __restrict__ C) {
  __shared__ alignas(16) unsigned char lds[131072];

  const int tid = threadIdx.x;
  const int w = tid >> 6, l = tid & 63;
  const int wr = w >> 2, wc = w & 3;  // 2x4 wave grid; per-wave 128x64 output
  const int bn = blockIdx.x, bm = blockIdx.y;

  const int rowq = tid >> 3;
  const int colb = ((l & 7) ^ (l >> 3)) << 4;
  const signed char* pA = A + (size_t)(bm * 256 + rowq) * K_TOTAL + colb;
  const signed char* pB = Bt + (size_t)(bn * 256 + rowq) * K_TOTAL + colb;
  unsigned char* const ldsp = lds;
  const int woff = w << 10;

#define SDA(b_, h_) (ldsp + (b_) * 65536 + (h_) * 16384 + woff)
#define SDB(b_, h_) (ldsp + (b_) * 65536 + 32768 + (h_) * 16384 + woff)
#define STAGE_A(b_, h_, t_)                                                    \
  do {                                                                         \
    GLOAD_LDS16(pA + (size_t)((h_) * 128) * K_TOTAL + (t_) * 128, SDA(b_, h_));\
    GLOAD_LDS16(pA + (size_t)((h_) * 128 + 64) * K_TOTAL + (t_) * 128,         \
                SDA(b_, h_) + 8192);                                           \
  } while (0)
#define STAGE_B(b_, h_, t_)                                                    \
  do {                                                                         \
    GLOAD_LDS16(pB + (size_t)((h_) * 128) * K_TOTAL + (t_) * 128, SDB(b_, h_));\
    GLOAD_LDS16(pB + (size_t)((h_) * 128 + 64) * K_TOTAL + (t_) * 128,         \
                SDB(b_, h_) + 8192);                                           \
  } while (0)

  const int arow = ((l & 15) << 7) + ((((l >> 4) ^ (l & 7)) & 7) << 4);

  i32x4 af[8];   // current m-half: 4 fm x 2 kk
  i32x4 bfr[8];  // whole-tile B: (nh*2+fn) x 2 kk
  i32x4 acc[8][4] = {{}};

#define RD_A(mh_)                                                             \
  do {                                                                        \
    const unsigned char* Ab_ = ldsp + bsel * 65536 + wr * 16384;              \
    _Pragma("unroll") for (int fm = 0; fm < 4; ++fm)                          \
        _Pragma("unroll") for (int kk = 0; kk < 2; ++kk)                      \
            af[fm * 2 + kk] = *(const i32x4*)(Ab_ + ((mh_) * 4 + fm) * 2048 + \
                                              (arow ^ (kk << 6)));            \
  } while (0)
#define RD_B(nh_)                                                             \
  do {                                                                        \
    const unsigned char* Bb_ = ldsp + bsel * 65536 + 32768 +                  \
                               (wc >> 1) * 16384 + (wc & 1) * 8192;           \
    _Pragma("unroll") for (int fn = 0; fn < 2; ++fn)                          \
        _Pragma("unroll") for (int kk = 0; kk < 2; ++kk)                      \
            bfr[((nh_) * 2 + fn) * 2 + kk] =                                  \
                *(const i32x4*)(Bb_ + ((nh_) * 2 + fn) * 2048 +               \
                                (arow ^ (kk << 6)));                          \
  } while (0)
#define QUAD(mh_, nh_)                                                        \
  do {                                                                        \
    _Pragma("unroll") for (int m = 0; m < 4; ++m)                             \
        _Pragma("unroll") for (int n = 0; n < 2; ++n)                         \
            _Pragma("unroll") for (int kk = 0; kk < 2; ++kk)                  \
                acc[(mh_) * 4 + m][(nh_) * 2 + n] =                           \
                    __builtin_amdgcn_mfma_i32_16x16x64_i8(                    \
                        af[m * 2 + kk], bfr[((nh_) * 2 + n) * 2 + kk],        \
                        acc[(mh_) * 4 + m][(nh_) * 2 + n], 0, 0, 0);          \
  } while (0)

  // --- prologue: tile0 + B(1) + A(1)h0; VM(6) drains tile0; fence-before-BAR ---
  STAGE_A(0, 0, 0); STAGE_A(0, 1, 0);
  STAGE_B(0, 0, 0); STAGE_B(0, 1, 0);
  STAGE_B(1, 0, 1); STAGE_B(1, 1, 1);
  STAGE_A(1, 0, 1);
  VM(6);
  BAR();

  // --- main loop (R7): 4 phases/tile, reads in consuming phase ---
  for (int t = 0; t < NT; ++t) {
    const int bsel = t & 1;
    // P1
    RD_A(0); RD_B(0);
    if (t + 1 < NT) STAGE_A(bsel ^ 1, 1, t + 1);
    BAR();
    QUAD(0, 0);
    BAR();
    // P2
    RD_B(1);
    if (t + 2 < NT) STAGE_B(bsel, 0, t + 2);
    BAR();
    QUAD(0, 1);
    BAR();
    // P3
    RD_A(1);
    if (t + 2 < NT) STAGE_B(bsel, 1, t + 2);
    BAR();
    QUAD(1, 1);
    BAR();
    // P4 (B-frags reused from registers)
    if (t + 2 < NT) STAGE_A(bsel, 0, t + 2);
    BAR();
    QUAD(1, 0);
    if (t < NT - 2) { VM(6); } else { VM(0); }
    BAR();
  }

  // --- epilogue: C/D col=lane&15, row=(lane>>4)*4+reg (dtype-independent);
  //     dequant acc * (ascale[row]*scales[col]) + bias ---
  const int row0 = bm * 256 + wr * 128 + ((l >> 4) << 2);
  const int col0 = bn * 256 + wc * 64 + (l & 15);
#pragma unroll
  for (int fn = 0; fn < 4; ++fn) {
    const int col = col0 + fn * 16;
    const float sc = scales[col];
    const float bi = bias[col];
#pragma unroll
    for (int fm = 0; fm < 8; ++fm) {
      const int r = row0 + fm * 16;
      float* cp = C + (size_t)r * N_TOTAL + col;
#pragma unroll
      for (int j = 0; j < 4; ++j)
        cp[(size_t)j * N_TOTAL] = fmaf((float)acc[fm][fn][j], ascale[r + j] * sc, bi);
    }
  }
}

// ---- guarded fallback (only if d_ws too small) ----
__global__ void naive_gemm(const float* __restrict__ A, const int* __restrict__ W,
                           const float* __restrict__ scales, const float* __restrict__ bias,
                           float* __restrict__ C) {
  size_t idx = (size_t)blockIdx.x * blockDim.x + threadIdx.x;
  if (idx >= (size_t)M_TOTAL * N_TOTAL) return;
  const int n = (int)(idx % N_TOTAL);
  const size_t m = idx / N_TOTAL;
  const float* a = A + m * (size_t)K_TOTAL;
  const int* w = W + (size_t)n * K_TOTAL;
  float s = 0.f;
  for (int k = 0; k < K_TOTAL; ++k) s = fmaf(a[k], (float)w[k], s);
  C[idx] = fmaf(s, scales[n], bias[n]);
}

extern "C" void kernel_launch(void* const* d_in, const int* in_sizes, int n_in,
                              void* d_out, int out_size, void* d_ws, size_t ws_size,
                              hipStream_t stream) {
  const float* A = (const float*)d_in[0];
  const int* W = (const int*)d_in[1];
  const float* scales = (const float*)d_in[2];
  const float* bias = (const float*)d_in[3];
  float* out = (float*)d_out;

  const size_t a_elems = (size_t)M_TOTAL * K_TOTAL;
  const size_t w_elems = (size_t)N_TOTAL * K_TOTAL;
  const size_t need = a_elems + w_elems + (size_t)M_TOTAL * sizeof(float);

  if (ws_size >= need) {
    signed char* A_q = (signed char*)d_ws;
    signed char* W_q = A_q + a_elems;
    float* a_s = (float*)(W_q + w_elems);
    cvt_fused<<<W_BLOCKS + M_TOTAL, 256, 0, stream>>>(A, (unsigned*)A_q, a_s, W,
                                                      (unsigned*)W_q);
    dim3 grid(N_TOTAL / 256, M_TOTAL / 256);  // (16, 64)
    w8a16_gemm_i8<<<grid, 512, 0, stream>>>(A_q, W_q, a_s, scales, bias, out);
  } else {
    size_t total = (size_t)M_TOTAL * N_TOTAL;
    naive_gemm<<<(unsigned)((total + 255) / 256), 256, 0, stream>>>(A, W, scales, bias, out);
  }
}

// Round 20
// 357.111 us; speedup vs baseline: 1.1352x; 1.0176x over previous
//
#include <hip/hip_runtime.h>
#include <hip/hip_bf16.h>

// out[B,S,O] = A[B,S,I] @ W[O,I]^T * scales[O] + bias[O]
// M = 16384, N = 4096, K = 4096. Output fp32.
// i8 path: A per-row quant (amax/127), W exact i8; mfma_i32_16x16x64_i8;
// dequant epilogue acc * (ascale[m]*scales[n]) + bias[n].
// R20 = R19 (GEMM 260us, no setprio) with 5 redundant barriers/tile removed
// (8 -> 3: end-P1, end-P2, end-P4+VM). Reads/stages/fences UNMOVED — the
// WAR/RAW proof is R7's verbatim; the deleted barriers only enforced
// lockstep. Fewer sync points let waves skew so one wave's LDS-read drain
// overlaps another's MFMA (the overlap intra-wave pipelining couldn't buy).
#define M_TOTAL 16384
#define N_TOTAL 4096
#define K_TOTAL 4096
#define NT (K_TOTAL / 128)  // 32 K-tiles of BK=128 (i8)
#define W_BLOCKS 2048

typedef __attribute__((ext_vector_type(4))) int i32x4;

__device__ __forceinline__ unsigned pack4(int a, int b, int c, int d) {
  return (a & 0xFF) | ((b & 0xFF) << 8) | ((c & 0xFF) << 16) | ((d & 0xFF) << 24);
}

// ---- fused conversions: blocks [0,W_BLOCKS) pack W, rest quantize A rows ----
__global__ __launch_bounds__(256) void cvt_fused(
    const float* __restrict__ A, unsigned* __restrict__ Aq,
    float* __restrict__ ascale, const int* __restrict__ W,
    unsigned* __restrict__ Wq) {
  const int tid = threadIdx.x;
  if (blockIdx.x < W_BLOCKS) {
    const int n4 = (N_TOTAL * K_TOTAL) / 4;
    const int stride = W_BLOCKS * 256;
    for (int i = blockIdx.x * 256 + tid; i < n4; i += stride) {
      int4 v = reinterpret_cast<const int4*>(W)[i];
      Wq[i] = pack4(v.x, v.y, v.z, v.w);
    }
    return;
  }
  const int row = blockIdx.x - W_BLOCKS;
  const float4* src = reinterpret_cast<const float4*>(A + (size_t)row * K_TOTAL);
  float4 v[4];
#pragma unroll
  for (int c = 0; c < 4; ++c) v[c] = src[tid + 256 * c];
  float amax = 0.0f;
#pragma unroll
  for (int c = 0; c < 4; ++c)
    amax = fmaxf(amax, fmaxf(fmaxf(fabsf(v[c].x), fabsf(v[c].y)),
                             fmaxf(fabsf(v[c].z), fabsf(v[c].w))));
#pragma unroll
  for (int off = 32; off > 0; off >>= 1) amax = fmaxf(amax, __shfl_xor(amax, off, 64));
  __shared__ float wmax[4];
  if ((tid & 63) == 0) wmax[tid >> 6] = amax;
  __syncthreads();
  amax = fmaxf(fmaxf(wmax[0], wmax[1]), fmaxf(wmax[2], wmax[3]));
  amax = fmaxf(amax, 1e-20f);
  const float rs = 127.0f / amax;
  if (tid == 0) ascale[row] = amax * (1.0f / 127.0f);

  unsigned* dst = Aq + (size_t)row * (K_TOTAL / 4);
#pragma unroll
  for (int c = 0; c < 4; ++c) {
    int q[4];
    float f[4] = {v[c].x, v[c].y, v[c].z, v[c].w};
#pragma unroll
    for (int i = 0; i < 4; ++i) {
      int t = (int)rintf(f[i] * rs);
      q[i] = t < -127 ? -127 : (t > 127 ? 127 : t);
    }
    dst[tid + 256 * c] = pack4(q[0], q[1], q[2], q[3]);
  }
}

// ======== 256x256 i8 GEMM — R7 skeleton, minimal barriers (R20) ========
#define GLOAD_LDS16(gp, lp)                                                \
  __builtin_amdgcn_global_load_lds(                                        \
      (const __attribute__((address_space(1))) void*)(gp),                 \
      (__attribute__((address_space(3))) void*)(lp), 16, 0, 0)

#define BAR() asm volatile("s_barrier" ::: "memory")
#define VM(n) asm volatile("s_waitcnt vmcnt(" #n ")" ::: "memory")

// LDS map (131072 B): buf b at b*65536: A_h0 [0,16K) A_h1 [16K,32K)
// B_h0 [32K,48K) B_h1 [48K,64K). Half-tile = 128 rows x 128 i8, stride 128 B.
// Swizzle: (r,c) at byte r*128 + (c ^ ((r&7)<<4)) (involution, 16B blocks).
// gload_lds writes linearly; GLOBAL source pre-inverse-swizzled (rule #21).
//
// Barrier-minimal schedule (stages/fences in R7's exact slots):
//  P1: RD_A(0) RD_B(0); STAGE_A(nxt,1,t+1); QUAD(0,0); BAR1
//  P2: RD_B(1);         STAGE_B(cur,0,t+2); QUAD(0,1); BAR2
//  P3: RD_A(1);         STAGE_B(cur,1,t+2); QUAD(1,1)        (no barrier)
//  P4:                  STAGE_A(cur,0,t+2); QUAD(1,0); VM(6); BAR3
// WAR proof (wave at a kept barrier has issued its QUADs => its reads are
// lgkm-drained): Ah1@P1 vs QUAD(1,1)(t-1) -> BAR3(t-1); Bh0@P2 vs
// QUAD(0,0) -> BAR1; Bh1@P3 vs QUAD(0,1) -> BAR2; Ah0@P4 vs QUAD(0,0)
// -> BAR1/BAR2. RAW: ledger unchanged from R7 (invariant 6 at P1 head,
// 14 at P4 -> VM(6) drains tile t+1 exactly; fence before BAR3, reads after).

__global__ __launch_bounds__(512, 2) void w8a16_gemm_i8(
    const signed char* __restrict__ A,   // [M][K] i8
    const signed char* __restrict__ Bt,  // [N][K] i8
    const float* __restrict__ ascale,    // [M]
    const float* __restrict__ scales, const float* __restrict__ bias,
    float* __restrict__ C) {
  __shared__ alignas(16) unsigned char lds[131072];

  const int tid = threadIdx.x;
  const int w = tid >> 6, l = tid & 63;
  const int wr = w >> 2, wc = w & 3;  // 2x4 wave grid; per-wave 128x64 output
  const int bn = blockIdx.x, bm = blockIdx.y;

  const int rowq = tid >> 3;
  const int colb = ((l & 7) ^ (l >> 3)) << 4;
  const signed char* pA = A + (size_t)(bm * 256 + rowq) * K_TOTAL + colb;
  const signed char* pB = Bt + (size_t)(bn * 256 + rowq) * K_TOTAL + colb;
  unsigned char* const ldsp = lds;
  const int woff = w << 10;

#define SDA(b_, h_) (ldsp + (b_) * 65536 + (h_) * 16384 + woff)
#define SDB(b_, h_) (ldsp + (b_) * 65536 + 32768 + (h_) * 16384 + woff)
#define STAGE_A(b_, h_, t_)                                                    \
  do {                                                                         \
    GLOAD_LDS16(pA + (size_t)((h_) * 128) * K_TOTAL + (t_) * 128, SDA(b_, h_));\
    GLOAD_LDS16(pA + (size_t)((h_) * 128 + 64) * K_TOTAL + (t_) * 128,         \
                SDA(b_, h_) + 8192);                                           \
  } while (0)
#define STAGE_B(b_, h_, t_)                                                    \
  do {                                                                         \
    GLOAD_LDS16(pB + (size_t)((h_) * 128) * K_TOTAL + (t_) * 128, SDB(b_, h_));\
    GLOAD_LDS16(pB + (size_t)((h_) * 128 + 64) * K_TOTAL + (t_) * 128,         \
                SDB(b_, h_) + 8192);                                           \
  } while (0)

  const int arow = ((l & 15) << 7) + ((((l >> 4) ^ (l & 7)) & 7) << 4);

  i32x4 af[8];   // current m-half: 4 fm x 2 kk
  i32x4 bfr[8];  // whole-tile B: (nh*2+fn) x 2 kk
  i32x4 acc[8][4] = {{}};

#define RD_A(mh_)                                                             \
  do {                                                                        \
    const unsigned char* Ab_ = ldsp + bsel * 65536 + wr * 16384;              \
    _Pragma("unroll") for (int fm = 0; fm < 4; ++fm)                          \
        _Pragma("unroll") for (int kk = 0; kk < 2; ++kk)                      \
            af[fm * 2 + kk] = *(const i32x4*)(Ab_ + ((mh_) * 4 + fm) * 2048 + \
                                              (arow ^ (kk << 6)));            \
  } while (0)
#define RD_B(nh_)                                                             \
  do {                                                                        \
    const unsigned char* Bb_ = ldsp + bsel * 65536 + 32768 +                  \
                               (wc >> 1) * 16384 + (wc & 1) * 8192;           \
    _Pragma("unroll") for (int fn = 0; fn < 2; ++fn)                          \
        _Pragma("unroll") for (int kk = 0; kk < 2; ++kk)                      \
            bfr[((nh_) * 2 + fn) * 2 + kk] =                                  \
                *(const i32x4*)(Bb_ + ((nh_) * 2 + fn) * 2048 +               \
                                (arow ^ (kk << 6)));                          \
  } while (0)
#define QUAD(mh_, nh_)                                                        \
  do {                                                                        \
    _Pragma("unroll") for (int m = 0; m < 4; ++m)                             \
        _Pragma("unroll") for (int n = 0; n < 2; ++n)                         \
            _Pragma("unroll") for (int kk = 0; kk < 2; ++kk)                  \
                acc[(mh_) * 4 + m][(nh_) * 2 + n] =                           \
                    __builtin_amdgcn_mfma_i32_16x16x64_i8(                    \
                        af[m * 2 + kk], bfr[((nh_) * 2 + n) * 2 + kk],        \
                        acc[(mh_) * 4 + m][(nh_) * 2 + n], 0, 0, 0);          \
  } while (0)

  // --- prologue: tile0 + B(1) + A(1)h0; VM(6) drains tile0; fence-before-BAR ---
  STAGE_A(0, 0, 0); STAGE_A(0, 1, 0);
  STAGE_B(0, 0, 0); STAGE_B(0, 1, 0);
  STAGE_B(1, 0, 1); STAGE_B(1, 1, 1);
  STAGE_A(1, 0, 1);
  VM(6);
  BAR();

  // --- main loop: 3 barriers/tile (proof in header comment) ---
  for (int t = 0; t < NT; ++t) {
    const int bsel = t & 1;
    // P1
    RD_A(0); RD_B(0);
    if (t + 1 < NT) STAGE_A(bsel ^ 1, 1, t + 1);
    QUAD(0, 0);
    BAR();  // BAR1: protects Bh0(cur) overwrite at P2
    // P2
    RD_B(1);
    if (t + 2 < NT) STAGE_B(bsel, 0, t + 2);
    QUAD(0, 1);
    BAR();  // BAR2: protects Bh1(cur) overwrite at P3
    // P3 (no barrier after)
    RD_A(1);
    if (t + 2 < NT) STAGE_B(bsel, 1, t + 2);
    QUAD(1, 1);
    // P4
    if (t + 2 < NT) STAGE_A(bsel, 0, t + 2);
    QUAD(1, 0);
    if (t < NT - 2) { VM(6); } else { VM(0); }
    BAR();  // BAR3: RAW gate for tile t+1 reads + Ah1(nxt) overwrite at P1'
  }

  // --- epilogue: C/D col=lane&15, row=(lane>>4)*4+reg (dtype-independent);
  //     dequant acc * (ascale[row]*scales[col]) + bias ---
  const int row0 = bm * 256 + wr * 128 + ((l >> 4) << 2);
  const int col0 = bn * 256 + wc * 64 + (l & 15);
#pragma unroll
  for (int fn = 0; fn < 4; ++fn) {
    const int col = col0 + fn * 16;
    const float sc = scales[col];
    const float bi = bias[col];
#pragma unroll
    for (int fm = 0; fm < 8; ++fm) {
      const int r = row0 + fm * 16;
      float* cp = C + (size_t)r * N_TOTAL + col;
#pragma unroll
      for (int j = 0; j < 4; ++j)
        cp[(size_t)j * N_TOTAL] = fmaf((float)acc[fm][fn][j], ascale[r + j] * sc, bi);
    }
  }
}

// ---- guarded fallback (only if d_ws too small) ----
__global__ void naive_gemm(const float* __restrict__ A, const int* __restrict__ W,
                           const float* __restrict__ scales, const float* __restrict__ bias,
                           float* __restrict__ C) {
  size_t idx = (size_t)blockIdx.x * blockDim.x + threadIdx.x;
  if (idx >= (size_t)M_TOTAL * N_TOTAL) return;
  const int n = (int)(idx % N_TOTAL);
  const size_t m = idx / N_TOTAL;
  const float* a = A + m * (size_t)K_TOTAL;
  const int* w = W + (size_t)n * K_TOTAL;
  float s = 0.f;
  for (int k = 0; k < K_TOTAL; ++k) s = fmaf(a[k], (float)w[k], s);
  C[idx] = fmaf(s, scales[n], bias[n]);
}

extern "C" void kernel_launch(void* const* d_in, const int* in_sizes, int n_in,
                              void* d_out, int out_size, void* d_ws, size_t ws_size,
                              hipStream_t stream) {
  const float* A = (const float*)d_in[0];
  const int* W = (const int*)d_in[1];
  const float* scales = (const float*)d_in[2];
  const float* bias = (const float*)d_in[3];
  float* out = (float*)d_out;

  const size_t a_elems = (size_t)M_TOTAL * K_TOTAL;
  const size_t w_elems = (size_t)N_TOTAL * K_TOTAL;
  const size_t need = a_elems + w_elems + (size_t)M_TOTAL * sizeof(float);

  if (ws_size >= need) {
    signed char* A_q = (signed char*)d_ws;
    signed char* W_q = A_q + a_elems;
    float* a_s = (float*)(W_q + w_elems);
    cvt_fused<<<W_BLOCKS + M_TOTAL, 256, 0, stream>>>(A, (unsigned*)A_q, a_s, W,
                                                      (unsigned*)W_q);
    dim3 grid(N_TOTAL / 256, M_TOTAL / 256);  // (16, 64)
    w8a16_gemm_i8<<<grid, 512, 0, stream>>>(A_q, W_q, a_s, scales, bias, out);
  } else {
    size_t total = (size_t)M_TOTAL * N_TOTAL;
    naive_gemm<<<(unsigned)((total + 255) / 256), 256, 0, stream>>>(A, W, scales, bias, out);
  }
}